// Round 21
// baseline (42.701 us; speedup 1.0000x reference)
//
#include <hip/hip_runtime.h>

#define BS  16
#define NN  256
#define HID 128

// K1: 256 blocks -> XCD x gets swz [32x,32x+32) = batches 2x,2x+1.
__device__ __forceinline__ int xcd_swz256(int bid) {
    return (bid & 7) * 32 + (bid >> 3);
}
// K2: 512 blocks -> XCD x gets swz [64x,64x+64) = batches 2x,2x+1.
__device__ __forceinline__ int xcd_swz512(int bid) {
    return (bid & 7) * 64 + (bid >> 3);
}

// ---------------------------------------------------------------------------
// K1: 256 blocks x 512 threads, 16 rows/block (1 block/CU -> weight delivery
// per CU halved vs 8-row tiles). 3 GEMV phases share a 32KB reduction buffer.
// Writes aiT, ajT (transposed) and g = h@W_out; h stays in LDS.
// ---------------------------------------------------------------------------
__global__ __launch_bounds__(512, 4) void gat_k1(
    const float* __restrict__ x, const float* __restrict__ W_fc,
    const float* __restrict__ b_fc, const float* __restrict__ W_a1,
    const float* __restrict__ b_a1, const float* __restrict__ W_out,
    float* __restrict__ aiT, float* __restrict__ ajT, float* __restrict__ g)
{
    __shared__ __align__(16) float xs[16][HID];           // 8KB
    __shared__ __align__(16) float hs[16][HID];           // 8KB
    __shared__ __align__(16) float red[4][16][HID];       // 32KB

    const int tid = threadIdx.x;
    const int k   = tid & 127;
    const int q   = tid >> 7;                 // 0..3
    const int swz = xcd_swz256(blockIdx.x);
    const int r0  = swz * 16;                 // flat row = b*NN + n0
    const int b   = r0 >> 8;
    const int n0  = r0 & 255;

    for (int t = tid; t < 16 * HID; t += 512)
        xs[t >> 7][t & 127] = x[r0 * HID + t];
    __syncthreads();

    // ---- phase 1: h partials, split-K quarter d in [32q, 32q+32) ----
    {
        float acc[16];
        #pragma unroll
        for (int r = 0; r < 16; ++r) acc[r] = 0.f;
        const int dq = 32 * q;
        #pragma unroll 2
        for (int d = 0; d < 32; d += 4) {
            float w[4];
            #pragma unroll
            for (int t = 0; t < 4; ++t) w[t] = W_fc[(dq + d + t) * HID + k];
            #pragma unroll
            for (int r = 0; r < 16; ++r) {
                const float4 xv = *(const float4*)&xs[r][dq + d];
                acc[r] += xv.x * w[0] + xv.y * w[1] + xv.z * w[2] + xv.w * w[3];
            }
        }
        #pragma unroll
        for (int r = 0; r < 16; ++r) red[q][r][k] = acc[r];
    }
    __syncthreads();

    // ---- reduce h: thread (k,q) -> rows 4q..4q+3 ----
    {
        const float bf = b_fc[k];
        #pragma unroll
        for (int r2 = 0; r2 < 4; ++r2) {
            const int r = 4 * q + r2;
            hs[r][k] = (red[0][r][k] + red[1][r][k])
                     + (red[2][r][k] + red[3][r][k]) + bf;
        }
    }
    __syncthreads();

    // ---- phase 2: q = (proj, d-half); 16 rows ----
    {
        const int is_aj = q >> 1;
        const int half  = q & 1;
        const float* Wp = W_a1 + (is_aj * HID + half * 64) * HID;
        float acc[16];
        #pragma unroll
        for (int r = 0; r < 16; ++r) acc[r] = 0.f;
        const int hb = half * 64;
        #pragma unroll 2
        for (int d = 0; d < 64; d += 4) {
            float w[4];
            #pragma unroll
            for (int t = 0; t < 4; ++t) w[t] = Wp[(d + t) * HID + k];
            #pragma unroll
            for (int r = 0; r < 16; ++r) {
                const float4 hv = *(const float4*)&hs[r][hb + d];
                acc[r] += hv.x * w[0] + hv.y * w[1] + hv.z * w[2] + hv.w * w[3];
            }
        }
        #pragma unroll
        for (int r = 0; r < 16; ++r) red[q][r][k] = acc[r];
    }
    __syncthreads();

    // ---- reduce + transposed store: q = (proj, row-oct of 8) ----
    {
        const int is_aj = q >> 1;
        const int rb8   = (q & 1) * 8;
        const float bias = is_aj ? 0.f : b_a1[k];
        const int p0 = 2 * is_aj, p1 = 2 * is_aj + 1;
        float v[8];
        #pragma unroll
        for (int t = 0; t < 8; ++t)
            v[t] = red[p0][rb8 + t][k] + red[p1][rb8 + t][k] + bias;
        float* dst = (is_aj ? ajT : aiT) + (b * HID + k) * NN + n0 + rb8;
        *(float4*)(dst + 0) = *(float4*)&v[0];
        *(float4*)(dst + 4) = *(float4*)&v[4];
    }
    __syncthreads();   // red free again

    // ---- phase 3: g partials, split-K quarters ----
    {
        float acc[16];
        #pragma unroll
        for (int r = 0; r < 16; ++r) acc[r] = 0.f;
        const int dq = 32 * q;
        #pragma unroll 2
        for (int d = 0; d < 32; d += 4) {
            float w[4];
            #pragma unroll
            for (int t = 0; t < 4; ++t) w[t] = W_out[(dq + d + t) * HID + k];
            #pragma unroll
            for (int r = 0; r < 16; ++r) {
                const float4 hv = *(const float4*)&hs[r][dq + d];
                acc[r] += hv.x * w[0] + hv.y * w[1] + hv.z * w[2] + hv.w * w[3];
            }
        }
        #pragma unroll
        for (int r = 0; r < 16; ++r) red[q][r][k] = acc[r];
    }
    __syncthreads();

    // ---- reduce g: thread (k,q) -> rows 4q..4q+3 ----
    {
        #pragma unroll
        for (int r2 = 0; r2 < 4; ++r2) {
            const int r = 4 * q + r2;
            g[(r0 + r) * HID + k] = (red[0][r][k] + red[1][r][k])
                                  + (red[2][r][k] + red[3][r][k]);
        }
    }
}

// ---------------------------------------------------------------------------
// K2: 512 blocks x 512 threads, 8-row i-tile. Phase A: wave = (k-quarter kh,
// j-half jh) — a TRUE PARTITION of (k,j): ajT read exactly ONCE per block
// (128KB, was 256). Lane owns a j-pair (float2, 512B coalesced). Phase B:
// j-octant waves, g read once (128KB). Softmax 1 row/wave.
// ---------------------------------------------------------------------------
__global__ __launch_bounds__(512, 4) void gat_k2(
    const float* __restrict__ aiT, const float* __restrict__ ajT,
    const float* __restrict__ g,  const int* __restrict__ adj,
    const float* __restrict__ w_a2, const float* __restrict__ b_a2,
    const float* __restrict__ b_out, float* __restrict__ out)
{
    __shared__ __align__(16) float4 aiwp[HID][2];        // 4KB {ai rows 0-3 | 4-7}
    __shared__ __align__(16) float  w2s[HID];            // 0.5KB
    __shared__ __align__(16) float  buf4[4][8][NN];      // 32KB e-partials; later red
    __shared__ __align__(16) float  ep[8][NN];           // 8KB p

    const int tid = threadIdx.x;
    const int swz = xcd_swz512(blockIdx.x);
    const int b   = swz >> 5;
    const int i0  = (swz & 31) * 8;
    const int wv  = tid >> 6, lane = tid & 63;

    // staging: aiwp[kk][rh] = ai rows i0+4rh .. i0+4rh+3
    if (tid < 256) {
        const int kk = tid >> 1, rh = tid & 1;
        aiwp[kk][rh] = *(const float4*)&aiT[(b * HID + kk) * NN + i0 + 4 * rh];
    } else if (tid < 384) {
        w2s[tid - 256] = w_a2[tid - 256];
    }
    // adj prefetch in softmax layout (row wv, cols 4*lane..+3)
    const int4 am = *(const int4*)(adj + (b * NN + i0 + wv) * NN + 4 * lane);
    __syncthreads();

    // ---- phase A: wave (kh = wv>>1, jh = wv&1): all 8 rows,
    //      kk in [32kh, 32kh+32), j in [128jh, 128jh+128), lane = j-pair ----
    {
        const int kh = wv >> 1, jh = wv & 1;
        const int kb = kh * 32, jb = jh * 128;
        const float* ajp = ajT + (b * HID + kb) * NN + jb + 2 * lane;
        float2 acc[8];
        #pragma unroll
        for (int r = 0; r < 8; ++r) { acc[r].x = 0.f; acc[r].y = 0.f; }
        float2 saw = {0.f, 0.f};
        #pragma unroll 8
        for (int t = 0; t < 32; ++t) {
            const float2 a2 = *(const float2*)(ajp + t * NN);
            const float4 aw0 = aiwp[kb + t][0];   // rows 0-3
            const float4 aw1 = aiwp[kb + t][1];   // rows 4-7
            const float wk   = w2s[kb + t];
            saw.x = __builtin_fmaf(a2.x, wk, saw.x);
            saw.y = __builtin_fmaf(a2.y, wk, saw.y);
            acc[0].x = __builtin_fmaf(fmaxf(aw0.x, -a2.x), wk, acc[0].x);
            acc[0].y = __builtin_fmaf(fmaxf(aw0.x, -a2.y), wk, acc[0].y);
            acc[1].x = __builtin_fmaf(fmaxf(aw0.y, -a2.x), wk, acc[1].x);
            acc[1].y = __builtin_fmaf(fmaxf(aw0.y, -a2.y), wk, acc[1].y);
            acc[2].x = __builtin_fmaf(fmaxf(aw0.z, -a2.x), wk, acc[2].x);
            acc[2].y = __builtin_fmaf(fmaxf(aw0.z, -a2.y), wk, acc[2].y);
            acc[3].x = __builtin_fmaf(fmaxf(aw0.w, -a2.x), wk, acc[3].x);
            acc[3].y = __builtin_fmaf(fmaxf(aw0.w, -a2.y), wk, acc[3].y);
            acc[4].x = __builtin_fmaf(fmaxf(aw1.x, -a2.x), wk, acc[4].x);
            acc[4].y = __builtin_fmaf(fmaxf(aw1.x, -a2.y), wk, acc[4].y);
            acc[5].x = __builtin_fmaf(fmaxf(aw1.y, -a2.x), wk, acc[5].x);
            acc[5].y = __builtin_fmaf(fmaxf(aw1.y, -a2.y), wk, acc[5].y);
            acc[6].x = __builtin_fmaf(fmaxf(aw1.z, -a2.x), wk, acc[6].x);
            acc[6].y = __builtin_fmaf(fmaxf(aw1.z, -a2.y), wk, acc[6].y);
            acc[7].x = __builtin_fmaf(fmaxf(aw1.w, -a2.x), wk, acc[7].x);
            acc[7].y = __builtin_fmaf(fmaxf(aw1.w, -a2.y), wk, acc[7].y);
        }
        #pragma unroll
        for (int r = 0; r < 8; ++r) {
            float2 e;
            e.x = acc[r].x + saw.x;
            e.y = acc[r].y + saw.y;
            *(float2*)&buf4[kh][r][jb + 2 * lane] = e;
        }
    }
    __syncthreads();

    // ---- mask + softmax: wave wv owns row wv (sum 4 k-quarter partials) ----
    {
        const float ba2 = b_a2[0];
        const float4 s0 = *(const float4*)&buf4[0][wv][4 * lane];
        const float4 s1 = *(const float4*)&buf4[1][wv][4 * lane];
        const float4 s2 = *(const float4*)&buf4[2][wv][4 * lane];
        const float4 s3 = *(const float4*)&buf4[3][wv][4 * lane];
        const float e0 = am.x ? (s0.x + s1.x) + (s2.x + s3.x) + ba2 : -1e9f;
        const float e1 = am.y ? (s0.y + s1.y) + (s2.y + s3.y) + ba2 : -1e9f;
        const float e2 = am.z ? (s0.z + s1.z) + (s2.z + s3.z) + ba2 : -1e9f;
        const float e3 = am.w ? (s0.w + s1.w) + (s2.w + s3.w) + ba2 : -1e9f;
        float m = fmaxf(fmaxf(e0, e1), fmaxf(e2, e3));
        #pragma unroll
        for (int off = 32; off; off >>= 1) m = fmaxf(m, __shfl_xor(m, off));
        const float p0 = __expf(e0 - m), p1 = __expf(e1 - m);
        const float p2 = __expf(e2 - m), p3 = __expf(e3 - m);
        float s = (p0 + p1) + (p2 + p3);
        #pragma unroll
        for (int off = 32; off; off >>= 1) s += __shfl_xor(s, off);
        const float inv = 1.f / s;
        const float4 pv = {p0 * inv, p1 * inv, p2 * inv, p3 * inv};
        *(float4*)&ep[wv][4 * lane] = pv;
    }
    __syncthreads();

    // ---- phase B: wave = j-octant [32wv,32wv+32), lane = k-pair, all 8
    //      rows -> g read exactly once per block ----
    float* red = &buf4[0][0][0];              // [8][8][HID] = 32KB, aliases buf4
    {
        float2 o[8];
        #pragma unroll
        for (int r = 0; r < 8; ++r) { o[r].x = 0.f; o[r].y = 0.f; }
        const int jb = 32 * wv;
        const float* gb = g + (b * NN + jb) * HID + 2 * lane;
        #pragma unroll 2
        for (int jq = 0; jq < 32; jq += 4) {
            const float2 g0 = *(const float2*)(gb + (jq + 0) * HID);
            const float2 g1 = *(const float2*)(gb + (jq + 1) * HID);
            const float2 g2 = *(const float2*)(gb + (jq + 2) * HID);
            const float2 g3 = *(const float2*)(gb + (jq + 3) * HID);
            #pragma unroll
            for (int r = 0; r < 8; ++r) {
                const float4 pv = *(const float4*)&ep[r][jb + jq];
                o[r].x += pv.x * g0.x + pv.y * g1.x + pv.z * g2.x + pv.w * g3.x;
                o[r].y += pv.x * g0.y + pv.y * g1.y + pv.z * g2.y + pv.w * g3.y;
            }
        }
        #pragma unroll
        for (int r = 0; r < 8; ++r)
            *(float2*)&red[(wv * 8 + r) * HID + 2 * lane] = o[r];
    }
    __syncthreads();

    // ---- final reduce: thread (k, q) -> rows 2q, 2q+1 (sum 8 octants) ----
    {
        const int k = tid & 127, q = tid >> 7;
        const float bo = b_out[k];
        #pragma unroll
        for (int r2 = 0; r2 < 2; ++r2) {
            const int r = 2 * q + r2;
            float s = 0.f;
            #pragma unroll
            for (int oct = 0; oct < 8; ++oct)
                s += red[(oct * 8 + r) * HID + k];
            out[(b * NN + i0 + r) * HID + k] = s + bo;
        }
    }
}

extern "C" void kernel_launch(void* const* d_in, const int* in_sizes, int n_in,
                              void* d_out, int out_size, void* d_ws, size_t ws_size,
                              hipStream_t stream) {
    const float* x     = (const float*)d_in[0];
    const int*   adj   = (const int*)  d_in[1];
    const float* W_fc  = (const float*)d_in[2];
    const float* b_fc  = (const float*)d_in[3];
    const float* W_a1  = (const float*)d_in[4];
    const float* b_a1  = (const float*)d_in[5];
    const float* w_a2  = (const float*)d_in[6];
    const float* b_a2  = (const float*)d_in[7];
    const float* W_out = (const float*)d_in[8];
    const float* b_out = (const float*)d_in[9];
    float* out = (float*)d_out;

    float* ws  = (float*)d_ws;
    float* aiT = ws;                      // aiT[b][k][n]
    float* ajT = ws + BS * NN * HID;      // ajT[b][k][n]
    float* g   = ws + 2 * BS * NN * HID;  // g = h@W_out, [b][n][k]

    gat_k1<<<BS * NN / 16, 512, 0, stream>>>(x, W_fc, b_fc, W_a1, b_a1, W_out,
                                             aiT, ajT, g);
    gat_k2<<<BS * (NN / 8), 512, 0, stream>>>(aiT, ajT, g, adj, w_a2, b_a2,
                                              b_out, out);
}

// Round 22
// 36.373 us; speedup vs baseline: 1.1740x; 1.1740x over previous
//
#include <hip/hip_runtime.h>

#define BS  16
#define NN  256
#define HID 128

// 512 blocks: XCD x gets swz in [64x, 64x+64) = batches 2x, 2x+1.
__device__ __forceinline__ int xcd_swz(int bid) {
    return (bid & 7) * 64 + (bid >> 3);
}

// ---------------------------------------------------------------------------
// K1: exact R16/R20 (part of the 36.0us best config). 512 blocks, 512
// threads, 8 rows/block. Split-K quarters; phase 2 fused ai+aj+g.
// ---------------------------------------------------------------------------
__global__ __launch_bounds__(512, 4) void gat_k1(
    const float* __restrict__ x, const float* __restrict__ W_fc,
    const float* __restrict__ b_fc, const float* __restrict__ W_a1,
    const float* __restrict__ b_a1, const float* __restrict__ W_out,
    float* __restrict__ aiT, float* __restrict__ ajT, float* __restrict__ g)
{
    __shared__ __align__(16) float xs[8][HID];            // 4KB
    __shared__ __align__(16) float hs[8][HID];            // 4KB
    __shared__ __align__(16) float red[4][3][8][HID];     // 48KB

    const int tid = threadIdx.x;
    const int k   = tid & 127;
    const int q   = tid >> 7;                 // 0..3
    const int swz = xcd_swz(blockIdx.x);
    const int r0  = swz * 8;                  // flat row = b*NN + n0
    const int b   = r0 >> 8;
    const int n0  = r0 & 255;

    for (int t = tid; t < 8 * HID; t += 512)
        xs[t >> 7][t & 127] = x[r0 * HID + t];
    __syncthreads();

    // ---- phase 1: h partials, split-K quarter d in [32q, 32q+32) ----
    {
        float acc[8] = {0,0,0,0,0,0,0,0};
        const int dq = 32 * q;
        #pragma unroll 2
        for (int d = 0; d < 32; d += 4) {
            float w[4];
            #pragma unroll
            for (int t = 0; t < 4; ++t) w[t] = W_fc[(dq + d + t) * HID + k];
            #pragma unroll
            for (int r = 0; r < 8; ++r) {
                const float4 xv = *(const float4*)&xs[r][dq + d];
                acc[r] += xv.x * w[0] + xv.y * w[1] + xv.z * w[2] + xv.w * w[3];
            }
        }
        #pragma unroll
        for (int r = 0; r < 8; ++r) red[q][0][r][k] = acc[r];
    }
    __syncthreads();

    // ---- reduce h: thread (k,q) -> rows 2q, 2q+1 ----
    {
        const float bf = b_fc[k];
        #pragma unroll
        for (int r2 = 0; r2 < 2; ++r2) {
            const int r = 2 * q + r2;
            hs[r][k] = (red[0][0][r][k] + red[1][0][r][k])
                     + (red[2][0][r][k] + red[3][0][r][k]) + bf;
        }
    }
    __syncthreads();

    // ---- phase 2 FUSED: ai+aj+g partials over d-quarter, one hs stream ----
    {
        float ai_a[8] = {0,0,0,0,0,0,0,0};
        float aj_a[8] = {0,0,0,0,0,0,0,0};
        float g_a[8]  = {0,0,0,0,0,0,0,0};
        const int dq = 32 * q;
        #pragma unroll 2
        for (int d = 0; d < 32; d += 4) {
            float wi[4], wj[4], wo[4];
            #pragma unroll
            for (int t = 0; t < 4; ++t) {
                wi[t] = W_a1[(dq + d + t) * HID + k];
                wj[t] = W_a1[(HID + dq + d + t) * HID + k];
                wo[t] = W_out[(dq + d + t) * HID + k];
            }
            #pragma unroll
            for (int r = 0; r < 8; ++r) {
                const float4 hv = *(const float4*)&hs[r][dq + d];
                ai_a[r] += hv.x * wi[0] + hv.y * wi[1] + hv.z * wi[2] + hv.w * wi[3];
                aj_a[r] += hv.x * wj[0] + hv.y * wj[1] + hv.z * wj[2] + hv.w * wj[3];
                g_a[r]  += hv.x * wo[0] + hv.y * wo[1] + hv.z * wo[2] + hv.w * wo[3];
            }
        }
        #pragma unroll
        for (int r = 0; r < 8; ++r) {
            red[q][0][r][k] = ai_a[r];
            red[q][1][r][k] = aj_a[r];
            red[q][2][r][k] = g_a[r];
        }
    }
    __syncthreads();

    // ---- reduce + stores ----
    {
        const int is_aj = q >> 1;
        const int rb4   = (q & 1) * 4;
        const float bias = is_aj ? 0.f : b_a1[k];
        float4 v;
        v.x = (red[0][is_aj][rb4 + 0][k] + red[1][is_aj][rb4 + 0][k])
            + (red[2][is_aj][rb4 + 0][k] + red[3][is_aj][rb4 + 0][k]) + bias;
        v.y = (red[0][is_aj][rb4 + 1][k] + red[1][is_aj][rb4 + 1][k])
            + (red[2][is_aj][rb4 + 1][k] + red[3][is_aj][rb4 + 1][k]) + bias;
        v.z = (red[0][is_aj][rb4 + 2][k] + red[1][is_aj][rb4 + 2][k])
            + (red[2][is_aj][rb4 + 2][k] + red[3][is_aj][rb4 + 2][k]) + bias;
        v.w = (red[0][is_aj][rb4 + 3][k] + red[1][is_aj][rb4 + 3][k])
            + (red[2][is_aj][rb4 + 3][k] + red[3][is_aj][rb4 + 3][k]) + bias;
        float* dst = (is_aj ? ajT : aiT) + (b * HID + k) * NN + n0 + rb4;
        *(float4*)dst = v;

        #pragma unroll
        for (int r2 = 0; r2 < 2; ++r2) {
            const int r = 2 * q + r2;
            g[(r0 + r) * HID + k] = (red[0][2][r][k] + red[1][2][r][k])
                                  + (red[2][2][r][k] + red[3][2][r][k]);
        }
    }
}

// ---------------------------------------------------------------------------
// K2: R21's true-partition variant. 512 blocks x 512 threads, 8-row i-tile.
// Phase A: wave = (k-quarter kh, j-half jh) — ajT read exactly ONCE per
// block (128KB). Phase B: j-octant waves, g read once (128KB). Softmax
// 1 row/wave.
// ---------------------------------------------------------------------------
__global__ __launch_bounds__(512, 4) void gat_k2(
    const float* __restrict__ aiT, const float* __restrict__ ajT,
    const float* __restrict__ g,  const int* __restrict__ adj,
    const float* __restrict__ w_a2, const float* __restrict__ b_a2,
    const float* __restrict__ b_out, float* __restrict__ out)
{
    __shared__ __align__(16) float4 aiwp[HID][2];        // 4KB {ai rows 0-3 | 4-7}
    __shared__ __align__(16) float  w2s[HID];            // 0.5KB
    __shared__ __align__(16) float  buf4[4][8][NN];      // 32KB e-partials; later red
    __shared__ __align__(16) float  ep[8][NN];           // 8KB p

    const int tid = threadIdx.x;
    const int swz = xcd_swz(blockIdx.x);
    const int b   = swz >> 5;
    const int i0  = (swz & 31) * 8;
    const int wv  = tid >> 6, lane = tid & 63;

    // staging: aiwp[kk][rh] = ai rows i0+4rh .. i0+4rh+3
    if (tid < 256) {
        const int kk = tid >> 1, rh = tid & 1;
        aiwp[kk][rh] = *(const float4*)&aiT[(b * HID + kk) * NN + i0 + 4 * rh];
    } else if (tid < 384) {
        w2s[tid - 256] = w_a2[tid - 256];
    }
    // adj prefetch in softmax layout (row wv, cols 4*lane..+3)
    const int4 am = *(const int4*)(adj + (b * NN + i0 + wv) * NN + 4 * lane);
    __syncthreads();

    // ---- phase A: wave (kh = wv>>1, jh = wv&1): all 8 rows,
    //      kk in [32kh, 32kh+32), j in [128jh, 128jh+128), lane = j-pair ----
    {
        const int kh = wv >> 1, jh = wv & 1;
        const int kb = kh * 32, jb = jh * 128;
        const float* ajp = ajT + (b * HID + kb) * NN + jb + 2 * lane;
        float2 acc[8];
        #pragma unroll
        for (int r = 0; r < 8; ++r) { acc[r].x = 0.f; acc[r].y = 0.f; }
        float2 saw = {0.f, 0.f};
        #pragma unroll 8
        for (int t = 0; t < 32; ++t) {
            const float2 a2 = *(const float2*)(ajp + t * NN);
            const float4 aw0 = aiwp[kb + t][0];   // rows 0-3
            const float4 aw1 = aiwp[kb + t][1];   // rows 4-7
            const float wk   = w2s[kb + t];
            saw.x = __builtin_fmaf(a2.x, wk, saw.x);
            saw.y = __builtin_fmaf(a2.y, wk, saw.y);
            acc[0].x = __builtin_fmaf(fmaxf(aw0.x, -a2.x), wk, acc[0].x);
            acc[0].y = __builtin_fmaf(fmaxf(aw0.x, -a2.y), wk, acc[0].y);
            acc[1].x = __builtin_fmaf(fmaxf(aw0.y, -a2.x), wk, acc[1].x);
            acc[1].y = __builtin_fmaf(fmaxf(aw0.y, -a2.y), wk, acc[1].y);
            acc[2].x = __builtin_fmaf(fmaxf(aw0.z, -a2.x), wk, acc[2].x);
            acc[2].y = __builtin_fmaf(fmaxf(aw0.z, -a2.y), wk, acc[2].y);
            acc[3].x = __builtin_fmaf(fmaxf(aw0.w, -a2.x), wk, acc[3].x);
            acc[3].y = __builtin_fmaf(fmaxf(aw0.w, -a2.y), wk, acc[3].y);
            acc[4].x = __builtin_fmaf(fmaxf(aw1.x, -a2.x), wk, acc[4].x);
            acc[4].y = __builtin_fmaf(fmaxf(aw1.x, -a2.y), wk, acc[4].y);
            acc[5].x = __builtin_fmaf(fmaxf(aw1.y, -a2.x), wk, acc[5].x);
            acc[5].y = __builtin_fmaf(fmaxf(aw1.y, -a2.y), wk, acc[5].y);
            acc[6].x = __builtin_fmaf(fmaxf(aw1.z, -a2.x), wk, acc[6].x);
            acc[6].y = __builtin_fmaf(fmaxf(aw1.z, -a2.y), wk, acc[6].y);
            acc[7].x = __builtin_fmaf(fmaxf(aw1.w, -a2.x), wk, acc[7].x);
            acc[7].y = __builtin_fmaf(fmaxf(aw1.w, -a2.y), wk, acc[7].y);
        }
        #pragma unroll
        for (int r = 0; r < 8; ++r) {
            float2 e;
            e.x = acc[r].x + saw.x;
            e.y = acc[r].y + saw.y;
            *(float2*)&buf4[kh][r][jb + 2 * lane] = e;
        }
    }
    __syncthreads();

    // ---- mask + softmax: wave wv owns row wv (sum 4 k-quarter partials) ----
    {
        const float ba2 = b_a2[0];
        const float4 s0 = *(const float4*)&buf4[0][wv][4 * lane];
        const float4 s1 = *(const float4*)&buf4[1][wv][4 * lane];
        const float4 s2 = *(const float4*)&buf4[2][wv][4 * lane];
        const float4 s3 = *(const float4*)&buf4[3][wv][4 * lane];
        const float e0 = am.x ? (s0.x + s1.x) + (s2.x + s3.x) + ba2 : -1e9f;
        const float e1 = am.y ? (s0.y + s1.y) + (s2.y + s3.y) + ba2 : -1e9f;
        const float e2 = am.z ? (s0.z + s1.z) + (s2.z + s3.z) + ba2 : -1e9f;
        const float e3 = am.w ? (s0.w + s1.w) + (s2.w + s3.w) + ba2 : -1e9f;
        float m = fmaxf(fmaxf(e0, e1), fmaxf(e2, e3));
        #pragma unroll
        for (int off = 32; off; off >>= 1) m = fmaxf(m, __shfl_xor(m, off));
        const float p0 = __expf(e0 - m), p1 = __expf(e1 - m);
        const float p2 = __expf(e2 - m), p3 = __expf(e3 - m);
        float s = (p0 + p1) + (p2 + p3);
        #pragma unroll
        for (int off = 32; off; off >>= 1) s += __shfl_xor(s, off);
        const float inv = 1.f / s;
        const float4 pv = {p0 * inv, p1 * inv, p2 * inv, p3 * inv};
        *(float4*)&ep[wv][4 * lane] = pv;
    }
    __syncthreads();

    // ---- phase B: wave = j-octant [32wv,32wv+32), lane = k-pair, all 8
    //      rows -> g read exactly once per block ----
    float* red = &buf4[0][0][0];              // [8][8][HID] = 32KB, aliases buf4
    {
        float2 o[8];
        #pragma unroll
        for (int r = 0; r < 8; ++r) { o[r].x = 0.f; o[r].y = 0.f; }
        const int jb = 32 * wv;
        const float* gb = g + (b * NN + jb) * HID + 2 * lane;
        #pragma unroll 2
        for (int jq = 0; jq < 32; jq += 4) {
            const float2 g0 = *(const float2*)(gb + (jq + 0) * HID);
            const float2 g1 = *(const float2*)(gb + (jq + 1) * HID);
            const float2 g2 = *(const float2*)(gb + (jq + 2) * HID);
            const float2 g3 = *(const float2*)(gb + (jq + 3) * HID);
            #pragma unroll
            for (int r = 0; r < 8; ++r) {
                const float4 pv = *(const float4*)&ep[r][jb + jq];
                o[r].x += pv.x * g0.x + pv.y * g1.x + pv.z * g2.x + pv.w * g3.x;
                o[r].y += pv.x * g0.y + pv.y * g1.y + pv.z * g2.y + pv.w * g3.y;
            }
        }
        #pragma unroll
        for (int r = 0; r < 8; ++r)
            *(float2*)&red[(wv * 8 + r) * HID + 2 * lane] = o[r];
    }
    __syncthreads();

    // ---- final reduce: thread (k, q) -> rows 2q, 2q+1 (sum 8 octants) ----
    {
        const int k = tid & 127, q = tid >> 7;
        const float bo = b_out[k];
        #pragma unroll
        for (int r2 = 0; r2 < 2; ++r2) {
            const int r = 2 * q + r2;
            float s = 0.f;
            #pragma unroll
            for (int oct = 0; oct < 8; ++oct)
                s += red[(oct * 8 + r) * HID + k];
            out[(b * NN + i0 + r) * HID + k] = s + bo;
        }
    }
}

extern "C" void kernel_launch(void* const* d_in, const int* in_sizes, int n_in,
                              void* d_out, int out_size, void* d_ws, size_t ws_size,
                              hipStream_t stream) {
    const float* x     = (const float*)d_in[0];
    const int*   adj   = (const int*)  d_in[1];
    const float* W_fc  = (const float*)d_in[2];
    const float* b_fc  = (const float*)d_in[3];
    const float* W_a1  = (const float*)d_in[4];
    const float* b_a1  = (const float*)d_in[5];
    const float* w_a2  = (const float*)d_in[6];
    const float* b_a2  = (const float*)d_in[7];
    const float* W_out = (const float*)d_in[8];
    const float* b_out = (const float*)d_in[9];
    float* out = (float*)d_out;

    float* ws  = (float*)d_ws;
    float* aiT = ws;                      // aiT[b][k][n]
    float* ajT = ws + BS * NN * HID;      // ajT[b][k][n]
    float* g   = ws + 2 * BS * NN * HID;  // g = h@W_out, [b][n][k]

    gat_k1<<<BS * NN / 8, 512, 0, stream>>>(x, W_fc, b_fc, W_a1, b_a1, W_out,
                                            aiT, ajT, g);
    gat_k2<<<BS * (NN / 8), 512, 0, stream>>>(aiT, ajT, g, adj, w_a2, b_a2,
                                              b_out, out);
}